// Round 13
// baseline (603.260 us; speedup 1.0000x reference)
//
#include <hip/hip_runtime.h>
#include <math.h>

#define NRW 131072
#define W   128
#define K   1024
#define C   4
#define BN  128
#define NT  1024

typedef _Float16 f16;
typedef _Float16 f16x8 __attribute__((ext_vector_type(8)));
typedef float    f32x4 __attribute__((ext_vector_type(4)));

__device__ __forceinline__ float fmulr(float a, float b){ return __fmul_rn(a,b); }
__device__ __forceinline__ float faddr(float a, float b){ return __fadd_rn(a,b); }
__device__ __forceinline__ float fsubr(float a, float b){ return __fsub_rn(a,b); }
__device__ __forceinline__ unsigned umin32(unsigned a, unsigned b){ return a < b ? a : b; }
__device__ __forceinline__ unsigned umax32(unsigned a, unsigned b){ return a > b ? a : b; }

// XLA:CPU reduce bits: acc = fl(acc + fl(v*v)), ascending, init 0
__device__ float seq_sumsq_glb(const float* __restrict__ p){
    float a = 0.f;
    for (int w = 0; w < W; ++w){ const float v = p[w]; a = faddr(a, fmulr(v, v)); }
    return a;
}

__global__ __launch_bounds__(256) void c2_kernel(const float* __restrict__ CB,
                                                 float* __restrict__ c2g){
    const int kg = blockIdx.x * 256 + threadIdx.x;
    if (kg < C * K) c2g[kg] = seq_sumsq_glb(CB + (size_t)kg * W);
}

// f16 hi/lo split, fragment-major B layout for mfma_f32_16x16x32_f16 (verified R9/R10):
// off = (((s*64 + (k>>4))*4 + q)*64 + ((w8&3)*16 + (k&15)))*8, q = w>>5, w8 = w>>3
__global__ __launch_bounds__(256) void split_kernel(const float* __restrict__ CB,
                                                    f16* __restrict__ Bh, f16* __restrict__ Bl){
    const int g  = blockIdx.x * 256 + threadIdx.x;     // 65536 total
    const int s  = g >> 14, k = (g >> 4) & 1023, w8 = g & 15;
    const float* src = CB + ((size_t)(s * K + k)) * W + w8 * 8;
    const size_t off = ((((size_t)(s * 64 + (k >> 4)) * 4 + (w8 >> 2)) * 64)
                        + ((w8 & 3) * 16 + (k & 15))) * 8;
    f16x8 hv, lv;
    #pragma unroll
    for (int j = 0; j < 8; ++j){
        const float x = src[j];
        const f16 h = (f16)x;
        hv[j] = h;
        lv[j] = (f16)(x - (float)h);
    }
    *(f16x8*)(Bh + off) = hv;
    *(f16x8*)(Bl + off) = lv;
}

#define DPP_TOP2(p1, p2, RCTL)                                                          \
    {                                                                                   \
        const unsigned q1 = (unsigned)__builtin_amdgcn_update_dpp((int)(p1), (int)(p1), \
                                                                  (RCTL), 0xF, 0xF, false); \
        const unsigned q2 = (unsigned)__builtin_amdgcn_update_dpp((int)(p2), (int)(p2), \
                                                                  (RCTL), 0xF, 0xF, false); \
        const unsigned t = umax32(p1, q1);                                              \
        p1 = umin32(p1, q1);                                                            \
        p2 = umin32(t, umin32(p2, q2));                                                 \
    }

#define PACK_INS(ACCV, C2V, KPK, S1, S2)                                                \
    {                                                                                   \
        const float sv = fmaf(-2.f, (ACCV), (C2V));                                     \
        const int   bb = __float_as_int(sv);                                            \
        const unsigned uu = ((unsigned)(bb ^ ((bb >> 31) | (int)0x80000000))            \
                             & 0xFFFFFC00u) | (KPK);                                    \
        const unsigned tmn = umin32((S1), uu);                                          \
        (S2) = umin32((S2), umax32((S1), uu));                                          \
        (S1) = tmn;                                                                     \
    }

__global__ __launch_bounds__(NT, 1) void rq13_kernel(
    const float* __restrict__ X, const float* __restrict__ CB,
    const float* __restrict__ c2g, const f16* __restrict__ BhG,
    const f16* __restrict__ BlG, float* __restrict__ out)
{
    __shared__ float Rt[BN][W + 1];                 // stride 129
    __shared__ __attribute__((aligned(16))) f16 AH[8 * 4 * 64 * 8];   // 32 KB A hi (frag-major)
    __shared__ __attribute__((aligned(16))) f16 AL[8 * 4 * 64 * 8];   // 32 KB A lo
    __shared__ unsigned long long mslot[BN * 17];   // [row][unit=wv], row stride 17
    __shared__ int   cand[BN][2];
    __shared__ float dve[BN][2];
    __shared__ int   widx[BN];

    const int tid = threadIdx.x;
    const int wv  = tid >> 6;      // 0..15: 64-k slice owner
    const int ln  = tid & 63;
    const int col = ln & 15;
    const int n0  = blockIdx.x * BN;

    // ---- initial residual = X ----
    for (int e = tid; e < BN * 32; e += NT){
        const int row = e >> 5, q = e & 31;
        const float4 v = *(const float4*)(X + (size_t)(n0 + row) * W + q * 4);
        float* rp = &Rt[row][q * 4];
        rp[0] = v.x; rp[1] = v.y; rp[2] = v.z; rp[3] = v.w;
    }

    for (int st = 0; st < C; ++st){
        const float*  cb  = CB + (size_t)st * K * W;
        const float4* cb4 = (const float4*)cb;

        __syncthreads();   // Rt stable

        // ---- extract A fragments -> f16 hi/lo LDS; init mslot ----
        for (int s = tid; s < 2048; s += NT){
            const int frag = s >> 6, lns = s & 63;
            const int row = ((frag >> 2) << 4) + (lns & 15);
            const int w0  = ((frag & 3) << 5) + ((lns >> 4) << 3);
            const float* rp = &Rt[row][w0];
            f16x8 h, l;
            #pragma unroll
            for (int j = 0; j < 8; ++j){
                const float x = rp[j];
                const f16 hh = (f16)x;
                h[j] = hh;
                l[j] = (f16)(x - (float)hh);
            }
            *(f16x8*)&AH[s * 8] = h;
            *(f16x8*)&AL[s * 8] = l;
        }
        for (int s = tid; s < BN * 17; s += NT) mslot[s] = ~0ull;
        __syncthreads();   // AH/AL + mslot ready

        // ---- MFMA scan: wave owns kb in [wv*4, wv*4+4); stream 1 kb of B at a time ----
        // per-stage fragment stride = 64 kb * 4 q * 64 lanes * 8 f16 = 131072 f16
        const f16* BhS = BhG + (size_t)st * 131072;
        const f16* BlS = BlG + (size_t)st * 131072;

        #pragma unroll 1
        for (int ch = 0; ch < 2; ++ch){
            unsigned s1a[4][4], s2a[4][4];
            #pragma unroll
            for (int a = 0; a < 4; ++a)
                #pragma unroll
                for (int b = 0; b < 4; ++b){ s1a[a][b] = 0xFFFFFFFFu; s2a[a][b] = 0xFFFFFFFFu; }

            #pragma unroll 1
            for (int kbi = 0; kbi < 4; ++kbi){
                const int kb = wv * 4 + kbi;
                f16x8 bh[4], bl[4];
                #pragma unroll
                for (int q = 0; q < 4; ++q){
                    const size_t fo = ((size_t)(kb * 4 + q) * 64 + ln) * 8;
                    bh[q] = *(const f16x8*)(BhS + fo);
                    bl[q] = *(const f16x8*)(BlS + fo);
                }
                const unsigned kpk = (unsigned)((kb << 4) + col);
                const float    c2v = c2g[st * K + (int)kpk];

                #pragma unroll 1
                for (int rbl = 0; rbl < 4; ++rbl){
                    const int rb = ch * 4 + rbl;
                    f32x4 acc = {0.f, 0.f, 0.f, 0.f};
                    {   // hi passes first (ah live), then lo pass (al reuses ah's regs)
                        f16x8 ah0 = *(const f16x8*)&AH[(((rb * 4 + 0) * 64) + ln) * 8];
                        f16x8 ah1 = *(const f16x8*)&AH[(((rb * 4 + 1) * 64) + ln) * 8];
                        f16x8 ah2 = *(const f16x8*)&AH[(((rb * 4 + 2) * 64) + ln) * 8];
                        f16x8 ah3 = *(const f16x8*)&AH[(((rb * 4 + 3) * 64) + ln) * 8];
                        acc = __builtin_amdgcn_mfma_f32_16x16x32_f16(ah0, bh[0], acc, 0, 0, 0);
                        acc = __builtin_amdgcn_mfma_f32_16x16x32_f16(ah1, bh[1], acc, 0, 0, 0);
                        acc = __builtin_amdgcn_mfma_f32_16x16x32_f16(ah2, bh[2], acc, 0, 0, 0);
                        acc = __builtin_amdgcn_mfma_f32_16x16x32_f16(ah3, bh[3], acc, 0, 0, 0);
                        acc = __builtin_amdgcn_mfma_f32_16x16x32_f16(ah0, bl[0], acc, 0, 0, 0);
                        acc = __builtin_amdgcn_mfma_f32_16x16x32_f16(ah1, bl[1], acc, 0, 0, 0);
                        acc = __builtin_amdgcn_mfma_f32_16x16x32_f16(ah2, bl[2], acc, 0, 0, 0);
                        acc = __builtin_amdgcn_mfma_f32_16x16x32_f16(ah3, bl[3], acc, 0, 0, 0);
                    }
                    {
                        f16x8 al0 = *(const f16x8*)&AL[(((rb * 4 + 0) * 64) + ln) * 8];
                        f16x8 al1 = *(const f16x8*)&AL[(((rb * 4 + 1) * 64) + ln) * 8];
                        f16x8 al2 = *(const f16x8*)&AL[(((rb * 4 + 2) * 64) + ln) * 8];
                        f16x8 al3 = *(const f16x8*)&AL[(((rb * 4 + 3) * 64) + ln) * 8];
                        acc = __builtin_amdgcn_mfma_f32_16x16x32_f16(al0, bh[0], acc, 0, 0, 0);
                        acc = __builtin_amdgcn_mfma_f32_16x16x32_f16(al1, bh[1], acc, 0, 0, 0);
                        acc = __builtin_amdgcn_mfma_f32_16x16x32_f16(al2, bh[2], acc, 0, 0, 0);
                        acc = __builtin_amdgcn_mfma_f32_16x16x32_f16(al3, bh[3], acc, 0, 0, 0);
                    }
                    if (rbl == 0){ PACK_INS(acc[0], c2v, kpk, s1a[0][0], s2a[0][0]);
                                   PACK_INS(acc[1], c2v, kpk, s1a[0][1], s2a[0][1]);
                                   PACK_INS(acc[2], c2v, kpk, s1a[0][2], s2a[0][2]);
                                   PACK_INS(acc[3], c2v, kpk, s1a[0][3], s2a[0][3]); }
                    if (rbl == 1){ PACK_INS(acc[0], c2v, kpk, s1a[1][0], s2a[1][0]);
                                   PACK_INS(acc[1], c2v, kpk, s1a[1][1], s2a[1][1]);
                                   PACK_INS(acc[2], c2v, kpk, s1a[1][2], s2a[1][2]);
                                   PACK_INS(acc[3], c2v, kpk, s1a[1][3], s2a[1][3]); }
                    if (rbl == 2){ PACK_INS(acc[0], c2v, kpk, s1a[2][0], s2a[2][0]);
                                   PACK_INS(acc[1], c2v, kpk, s1a[2][1], s2a[2][1]);
                                   PACK_INS(acc[2], c2v, kpk, s1a[2][2], s2a[2][2]);
                                   PACK_INS(acc[3], c2v, kpk, s1a[2][3], s2a[2][3]); }
                    if (rbl == 3){ PACK_INS(acc[0], c2v, kpk, s1a[3][0], s2a[3][0]);
                                   PACK_INS(acc[1], c2v, kpk, s1a[3][1], s2a[3][1]);
                                   PACK_INS(acc[2], c2v, kpk, s1a[3][2], s2a[3][2]);
                                   PACK_INS(acc[3], c2v, kpk, s1a[3][3], s2a[3][3]); }
                }
            }

            // flush: DPP top-2 across the 16 col-lanes, write unit slot
            #pragma unroll
            for (int rbl = 0; rbl < 4; ++rbl){
                #pragma unroll
                for (int rg = 0; rg < 4; ++rg){
                    unsigned p1 = s1a[rbl][rg], p2 = s2a[rbl][rg];
                    DPP_TOP2(p1, p2, 0x121)   // row_ror:1
                    DPP_TOP2(p1, p2, 0x122)   // row_ror:2
                    DPP_TOP2(p1, p2, 0x124)   // row_ror:4
                    DPP_TOP2(p1, p2, 0x128)   // row_ror:8
                    if (col == 0){
                        const int row = (ch * 4 + rbl) * 16 + ((ln >> 4) << 2) + rg;
                        mslot[row * 17 + wv] =
                            ((unsigned long long)p2 << 32) | (unsigned long long)p1;
                    }
                }
            }
        }
        __syncthreads();   // all unit top-2 written

        // ---- final merge: top-2 over 16 units (32 packed values) per row ----
        if (tid < BN){
            unsigned b1 = 0xFFFFFFFFu, b2 = 0xFFFFFFFFu;
            for (int i = 0; i < 16; ++i){
                const int ii = (i + tid) & 15;
                const unsigned long long v = mslot[tid * 17 + ii];
                const unsigned lo = (unsigned)v, hi = (unsigned)(v >> 32);
                if (lo < b1){ b2 = b1; b1 = lo; } else if (lo < b2) b2 = lo;
                if (hi < b1){ b2 = b1; b1 = hi; } else if (hi < b2) b2 = hi;
            }
            cand[tid][0] = (int)(b1 & 1023u);
            cand[tid][1] = (int)(b2 & 1023u);
        }
        __syncthreads();

        // ---- exact XLA-bits re-eval of both candidates ----
        if (tid < 2 * BN){
            const int row = tid >> 1, cd = tid & 1;
            const int k = cand[row][cd];
            const float* cw = cb + (size_t)k * W;
            float r2 = 0.f, dot = 0.f;
            for (int w = 0; w < W; ++w){
                const float rv = Rt[row][w];
                r2  = faddr(r2, fmulr(rv, rv));
                dot = __fmaf_rn(rv, cw[w], dot);
            }
            dve[row][cd] = faddr(fsubr(r2, faddr(dot, dot)), c2g[st * K + k]);
        }
        __syncthreads();

        // ---- decide (lexicographic: XLA first-min) + outputs ----
        if (tid < BN){
            const float a0 = dve[tid][0], a1 = dve[tid][1];
            const int   i0 = cand[tid][0], i1 = cand[tid][1];
            int wi; float wd;
            if (a1 < a0 || (a1 == a0 && i1 < i0)){ wi = i1; wd = a1; } else { wi = i0; wd = a0; }
            widx[tid] = wi;
            out[(size_t)st * NRW + (n0 + tid)] = (float)wi;
            out[(size_t)C * NRW + (size_t)(n0 + tid) * C + st] = __fsqrt_rn(fmaxf(wd, 0.f));
        }
        __syncthreads();

        // ---- residual -= cb[idx], elementwise f32 (bit-exact) ----
        if (st < C - 1){
            for (int e = tid; e < BN * 32; e += NT){
                const int row = e >> 5, q = e & 31;
                const float4 v = cb4[(size_t)widx[row] * 32 + q];
                float* rp = &Rt[row][q * 4];
                rp[0] = fsubr(rp[0], v.x);
                rp[1] = fsubr(rp[1], v.y);
                rp[2] = fsubr(rp[2], v.z);
                rp[3] = fsubr(rp[3], v.w);
            }
        }
    }
}

extern "C" void kernel_launch(void* const* d_in, const int* in_sizes, int n_in,
                              void* d_out, int out_size, void* d_ws, size_t ws_size,
                              hipStream_t stream) {
    const float* X  = (const float*)d_in[0];
    const float* CB = (const float*)d_in[1];
    float* out = (float*)d_out;

    float* c2g = (float*)d_ws;                              // 16 KB
    f16*   Bh  = (f16*)((char*)d_ws + 16384);               // 1 MB
    f16*   Bl  = (f16*)((char*)d_ws + 16384 + 1048576);     // 1 MB

    c2_kernel<<<dim3((C * K + 255) / 256), 256, 0, stream>>>(CB, c2g);
    split_kernel<<<dim3(C * K * 16 / 256), 256, 0, stream>>>(CB, Bh, Bl);
    rq13_kernel<<<dim3(NRW / BN), NT, 0, stream>>>(X, CB, c2g, Bh, Bl, out);
}

// Round 14
// 471.023 us; speedup vs baseline: 1.2807x; 1.2807x over previous
//
#include <hip/hip_runtime.h>
#include <math.h>

#define NRW 131072
#define W   128
#define K   1024
#define C   4
#define BN  128
#define NT  512

typedef _Float16 f16;
typedef _Float16 f16x8 __attribute__((ext_vector_type(8)));
typedef float    f32x4 __attribute__((ext_vector_type(4)));

__device__ __forceinline__ float fmulr(float a, float b){ return __fmul_rn(a,b); }
__device__ __forceinline__ float faddr(float a, float b){ return __fadd_rn(a,b); }
__device__ __forceinline__ float fsubr(float a, float b){ return __fsub_rn(a,b); }
__device__ __forceinline__ unsigned umin32(unsigned a, unsigned b){ return a < b ? a : b; }
__device__ __forceinline__ unsigned umax32(unsigned a, unsigned b){ return a > b ? a : b; }

// XLA:CPU reduce bits: acc = fl(acc + fl(v*v)), ascending, init 0
__device__ float seq_sumsq_glb(const float* __restrict__ p){
    float a = 0.f;
    for (int w = 0; w < W; ++w){ const float v = p[w]; a = faddr(a, fmulr(v, v)); }
    return a;
}

__global__ __launch_bounds__(256) void c2_kernel(const float* __restrict__ CB,
                                                 float* __restrict__ c2g){
    const int kg = blockIdx.x * 256 + threadIdx.x;
    if (kg < C * K) c2g[kg] = seq_sumsq_glb(CB + (size_t)kg * W);
}

// f16 hi-only, fragment-major B layout for mfma_f32_16x16x32_f16 (verified R9/R10/R12):
// off = (((s*64 + (k>>4))*4 + q)*64 + ((w8&3)*16 + (k&15)))*8, q = w>>5, w8 = w>>3
__global__ __launch_bounds__(256) void split_kernel(const float* __restrict__ CB,
                                                    f16* __restrict__ Bh){
    const int g  = blockIdx.x * 256 + threadIdx.x;     // 65536 total
    const int s  = g >> 14, k = (g >> 4) & 1023, w8 = g & 15;
    const float* src = CB + ((size_t)(s * K + k)) * W + w8 * 8;
    const size_t off = ((((size_t)(s * 64 + (k >> 4)) * 4 + (w8 >> 2)) * 64)
                        + ((w8 & 3) * 16 + (k & 15))) * 8;
    f16x8 hv;
    #pragma unroll
    for (int j = 0; j < 8; ++j) hv[j] = (f16)src[j];
    *(f16x8*)(Bh + off) = hv;
}

#define DPP_TOP2(p1, p2, RCTL)                                                          \
    {                                                                                   \
        const unsigned q1 = (unsigned)__builtin_amdgcn_update_dpp((int)(p1), (int)(p1), \
                                                                  (RCTL), 0xF, 0xF, false); \
        const unsigned q2 = (unsigned)__builtin_amdgcn_update_dpp((int)(p2), (int)(p2), \
                                                                  (RCTL), 0xF, 0xF, false); \
        const unsigned t = umax32(p1, q1);                                              \
        p1 = umin32(p1, q1);                                                            \
        p2 = umin32(t, umin32(p2, q2));                                                 \
    }

#define PACK_INS(ACCV, C2V, KPK, S1, S2)                                                \
    {                                                                                   \
        const float sv = fmaf(-2.f, (ACCV), (C2V));                                     \
        const int   bb = __float_as_int(sv);                                            \
        const unsigned uu = ((unsigned)(bb ^ ((bb >> 31) | (int)0x80000000))            \
                             & 0xFFFFFC00u) | (KPK);                                    \
        const unsigned tmn = umin32((S1), uu);                                          \
        (S2) = umin32((S2), umax32((S1), uu));                                          \
        (S1) = tmn;                                                                     \
    }

#define INS4(VAL, C0, C1, C2, C3)                                                       \
    {                                                                                   \
        const unsigned v_ = (VAL);                                                      \
        if (v_ < (C3)){                                                                 \
            if (v_ < (C2)){ (C3) = (C2);                                                \
                if (v_ < (C1)){ (C2) = (C1);                                            \
                    if (v_ < (C0)){ (C1) = (C0); (C0) = v_; } else (C1) = v_;           \
                } else (C2) = v_;                                                       \
            } else (C3) = v_;                                                           \
        }                                                                               \
    }

__global__ __launch_bounds__(NT, 2) void rq14_kernel(
    const float* __restrict__ X, const float* __restrict__ CB,
    const float* __restrict__ c2g, const f16* __restrict__ BhG,
    float* __restrict__ out)
{
    __shared__ float Rt[BN][W + 1];                  // 66 KB, stride 129
    __shared__ unsigned long long mslot[BN * 9];     // 9 KB: [row][wv], stride 9
    __shared__ int   cand[BN][4];
    __shared__ float dve[BN][4];
    __shared__ int   widx[BN];

    const int tid = threadIdx.x;
    const int wv  = tid >> 6;      // 0..7: owns kb in [wv*8, wv*8+8)
    const int ln  = tid & 63;
    const int col = ln & 15;
    const int n0  = blockIdx.x * BN;

    // ---- initial residual = X ----
    for (int e = tid; e < BN * 32; e += NT){
        const int row = e >> 5, q = e & 31;
        const float4 v = *(const float4*)(X + (size_t)(n0 + row) * W + q * 4);
        float* rp = &Rt[row][q * 4];
        rp[0] = v.x; rp[1] = v.y; rp[2] = v.z; rp[3] = v.w;
    }

    for (int st = 0; st < C; ++st){
        const float*  cb  = CB + (size_t)st * K * W;
        const float4* cb4 = (const float4*)cb;
        const f16*    BhS = BhG + (size_t)st * 131072;   // 64 kb * 4 q * 64 ln * 8

        __syncthreads();   // Rt stable

        // ---- MFMA scan: ch = row-half; A-hi in regs; B-hi streamed per kb ----
        #pragma unroll 1
        for (int ch = 0; ch < 2; ++ch){
            // A fragments: rows [ch*64, ch*64+64), direct f32->f16 from Rt
            f16x8 a[4][4];
            #pragma unroll
            for (int rbl = 0; rbl < 4; ++rbl){
                #pragma unroll
                for (int q = 0; q < 4; ++q){
                    const int row = ch * 64 + rbl * 16 + (ln & 15);
                    const int w0  = q * 32 + ((ln >> 4) << 3);
                    const float* rp = &Rt[row][w0];
                    f16x8 h;
                    #pragma unroll
                    for (int j = 0; j < 8; ++j) h[j] = (f16)rp[j];
                    a[rbl][q] = h;
                }
            }

            unsigned s1[4][4], s2[4][4];
            #pragma unroll
            for (int i = 0; i < 4; ++i)
                #pragma unroll
                for (int j = 0; j < 4; ++j){ s1[i][j] = 0xFFFFFFFFu; s2[i][j] = 0xFFFFFFFFu; }

            #pragma unroll 1
            for (int kbi = 0; kbi < 8; ++kbi){
                const int kb = wv * 8 + kbi;
                f16x8 bh0 = *(const f16x8*)(BhS + ((size_t)(kb * 4 + 0) * 64 + ln) * 8);
                f16x8 bh1 = *(const f16x8*)(BhS + ((size_t)(kb * 4 + 1) * 64 + ln) * 8);
                f16x8 bh2 = *(const f16x8*)(BhS + ((size_t)(kb * 4 + 2) * 64 + ln) * 8);
                f16x8 bh3 = *(const f16x8*)(BhS + ((size_t)(kb * 4 + 3) * 64 + ln) * 8);
                const unsigned kpk = (unsigned)((kb << 4) + col);
                const float    c2v = c2g[st * K + (int)kpk];

                #pragma unroll
                for (int rbl = 0; rbl < 4; ++rbl){
                    f32x4 acc = {0.f, 0.f, 0.f, 0.f};
                    acc = __builtin_amdgcn_mfma_f32_16x16x32_f16(a[rbl][0], bh0, acc, 0, 0, 0);
                    acc = __builtin_amdgcn_mfma_f32_16x16x32_f16(a[rbl][1], bh1, acc, 0, 0, 0);
                    acc = __builtin_amdgcn_mfma_f32_16x16x32_f16(a[rbl][2], bh2, acc, 0, 0, 0);
                    acc = __builtin_amdgcn_mfma_f32_16x16x32_f16(a[rbl][3], bh3, acc, 0, 0, 0);
                    PACK_INS(acc[0], c2v, kpk, s1[rbl][0], s2[rbl][0]);
                    PACK_INS(acc[1], c2v, kpk, s1[rbl][1], s2[rbl][1]);
                    PACK_INS(acc[2], c2v, kpk, s1[rbl][2], s2[rbl][2]);
                    PACK_INS(acc[3], c2v, kpk, s1[rbl][3], s2[rbl][3]);
                }
            }

            // flush: DPP top-2 across the 16 col-lanes -> per-wave slot
            #pragma unroll
            for (int rbl = 0; rbl < 4; ++rbl){
                #pragma unroll
                for (int rg = 0; rg < 4; ++rg){
                    unsigned p1 = s1[rbl][rg], p2 = s2[rbl][rg];
                    DPP_TOP2(p1, p2, 0x121)   // row_ror:1
                    DPP_TOP2(p1, p2, 0x122)   // row_ror:2
                    DPP_TOP2(p1, p2, 0x124)   // row_ror:4
                    DPP_TOP2(p1, p2, 0x128)   // row_ror:8
                    if (col == 0){
                        const int row = ch * 64 + rbl * 16 + ((ln >> 4) << 2) + rg;
                        mslot[row * 9 + wv] =
                            ((unsigned long long)p2 << 32) | (unsigned long long)p1;
                    }
                }
            }
        }
        __syncthreads();   // all wave top-2 written

        // ---- merge: global top-4 per row from 8 waves x top-2 ----
        if (tid < BN){
            unsigned c0 = 0xFFFFFFFFu, c1 = 0xFFFFFFFFu, c2m = 0xFFFFFFFFu, c3 = 0xFFFFFFFFu;
            #pragma unroll
            for (int i = 0; i < 8; ++i){
                const unsigned long long v = mslot[tid * 9 + i];
                const unsigned lo = (unsigned)v, hi = (unsigned)(v >> 32);
                INS4(lo, c0, c1, c2m, c3);
                INS4(hi, c0, c1, c2m, c3);
            }
            cand[tid][0] = (int)(c0 & 1023u);
            cand[tid][1] = (int)(c1 & 1023u);
            cand[tid][2] = (int)(c2m & 1023u);
            cand[tid][3] = (int)(c3 & 1023u);
        }
        __syncthreads();

        // ---- exact XLA-bits re-eval of 4 candidates (512 threads = 128 rows x 4) ----
        {
            const int row = tid >> 2, cd = tid & 3;
            const int k = cand[row][cd];
            const float* cw = cb + (size_t)k * W;
            float r2 = 0.f, dot = 0.f;
            for (int w = 0; w < W; ++w){
                const float rv = Rt[row][w];
                r2  = faddr(r2, fmulr(rv, rv));
                dot = __fmaf_rn(rv, cw[w], dot);
            }
            dve[row][cd] = faddr(fsubr(r2, faddr(dot, dot)), c2g[st * K + k]);
        }
        __syncthreads();

        // ---- decide: lexicographic (d2, k) min among 4 = XLA first-min ----
        if (tid < BN){
            float bd = dve[tid][0]; int bk = cand[tid][0];
            #pragma unroll
            for (int j = 1; j < 4; ++j){
                const float d = dve[tid][j]; const int k = cand[tid][j];
                if (d < bd || (d == bd && k < bk)){ bd = d; bk = k; }
            }
            widx[tid] = bk;
            out[(size_t)st * NRW + (n0 + tid)] = (float)bk;
            out[(size_t)C * NRW + (size_t)(n0 + tid) * C + st] = __fsqrt_rn(fmaxf(bd, 0.f));
        }
        __syncthreads();

        // ---- residual -= cb[idx], elementwise f32 (bit-exact) ----
        if (st < C - 1){
            for (int e = tid; e < BN * 32; e += NT){
                const int row = e >> 5, q = e & 31;
                const float4 v = cb4[(size_t)widx[row] * 32 + q];
                float* rp = &Rt[row][q * 4];
                rp[0] = fsubr(rp[0], v.x);
                rp[1] = fsubr(rp[1], v.y);
                rp[2] = fsubr(rp[2], v.z);
                rp[3] = fsubr(rp[3], v.w);
            }
        }
    }
}

extern "C" void kernel_launch(void* const* d_in, const int* in_sizes, int n_in,
                              void* d_out, int out_size, void* d_ws, size_t ws_size,
                              hipStream_t stream) {
    const float* X  = (const float*)d_in[0];
    const float* CB = (const float*)d_in[1];
    float* out = (float*)d_out;

    float* c2g = (float*)d_ws;                    // 16 KB
    f16*   Bh  = (f16*)((char*)d_ws + 16384);     // 1 MB

    c2_kernel<<<dim3((C * K + 255) / 256), 256, 0, stream>>>(CB, c2g);
    split_kernel<<<dim3(C * K * 16 / 256), 256, 0, stream>>>(CB, Bh);
    rq14_kernel<<<dim3(NRW / BN), NT, 0, stream>>>(X, CB, c2g, Bh, out);
}

// Round 15
// 335.702 us; speedup vs baseline: 1.7970x; 1.4031x over previous
//
#include <hip/hip_runtime.h>
#include <math.h>

#define NRW 131072
#define W   128
#define K   1024
#define C   4
#define BN  64
#define NT  256

typedef _Float16 f16;
typedef _Float16 f16x8 __attribute__((ext_vector_type(8)));
typedef float    f32x4 __attribute__((ext_vector_type(4)));

__device__ __forceinline__ float fmulr(float a, float b){ return __fmul_rn(a,b); }
__device__ __forceinline__ float faddr(float a, float b){ return __fadd_rn(a,b); }
__device__ __forceinline__ float fsubr(float a, float b){ return __fsub_rn(a,b); }
__device__ __forceinline__ unsigned umin32(unsigned a, unsigned b){ return a < b ? a : b; }
__device__ __forceinline__ unsigned umax32(unsigned a, unsigned b){ return a > b ? a : b; }

// XLA:CPU reduce bits: acc = fl(acc + fl(v*v)), ascending, init 0
__device__ float seq_sumsq_glb(const float* __restrict__ p){
    float a = 0.f;
    for (int w = 0; w < W; ++w){ const float v = p[w]; a = faddr(a, fmulr(v, v)); }
    return a;
}

__global__ __launch_bounds__(256) void c2_kernel(const float* __restrict__ CB,
                                                 float* __restrict__ c2g){
    const int kg = blockIdx.x * 256 + threadIdx.x;
    if (kg < C * K) c2g[kg] = seq_sumsq_glb(CB + (size_t)kg * W);
}

// f16 hi-only, fragment-major B layout for mfma_f32_16x16x32_f16 (verified R9-R14):
// off = (((s*64 + (k>>4))*4 + q)*64 + ((w8&3)*16 + (k&15)))*8, q = w>>5, w8 = w>>3
__global__ __launch_bounds__(256) void split_kernel(const float* __restrict__ CB,
                                                    f16* __restrict__ Bh){
    const int g  = blockIdx.x * 256 + threadIdx.x;     // 65536 total
    const int s  = g >> 14, k = (g >> 4) & 1023, w8 = g & 15;
    const float* src = CB + ((size_t)(s * K + k)) * W + w8 * 8;
    const size_t off = ((((size_t)(s * 64 + (k >> 4)) * 4 + (w8 >> 2)) * 64)
                        + ((w8 & 3) * 16 + (k & 15))) * 8;
    f16x8 hv;
    #pragma unroll
    for (int j = 0; j < 8; ++j) hv[j] = (f16)src[j];
    *(f16x8*)(Bh + off) = hv;
}

#define DPP_TOP2(p1, p2, RCTL)                                                          \
    {                                                                                   \
        const unsigned q1 = (unsigned)__builtin_amdgcn_update_dpp((int)(p1), (int)(p1), \
                                                                  (RCTL), 0xF, 0xF, false); \
        const unsigned q2 = (unsigned)__builtin_amdgcn_update_dpp((int)(p2), (int)(p2), \
                                                                  (RCTL), 0xF, 0xF, false); \
        const unsigned t = umax32(p1, q1);                                              \
        p1 = umin32(p1, q1);                                                            \
        p2 = umin32(t, umin32(p2, q2));                                                 \
    }

#define PACK_INS(ACCV, C2V, KPK, S1, S2)                                                \
    {                                                                                   \
        const float sv = fmaf(-2.f, (ACCV), (C2V));                                     \
        const int   bb = __float_as_int(sv);                                            \
        const unsigned uu = ((unsigned)(bb ^ ((bb >> 31) | (int)0x80000000))            \
                             & 0xFFFFFC00u) | (KPK);                                    \
        const unsigned tmn = umin32((S1), uu);                                          \
        (S2) = umin32((S2), umax32((S1), uu));                                          \
        (S1) = tmn;                                                                     \
    }

#define INS4(VAL, C0, C1, C2, C3)                                                       \
    {                                                                                   \
        const unsigned v_ = (VAL);                                                      \
        if (v_ < (C3)){                                                                 \
            if (v_ < (C2)){ (C3) = (C2);                                                \
                if (v_ < (C1)){ (C2) = (C1);                                            \
                    if (v_ < (C0)){ (C1) = (C0); (C0) = v_; } else (C1) = v_;           \
                } else (C2) = v_;                                                       \
            } else (C3) = v_;                                                           \
        }                                                                               \
    }

__global__ __launch_bounds__(NT, 3) void rq15_kernel(
    const float* __restrict__ X, const float* __restrict__ CB,
    const float* __restrict__ c2g, const f16* __restrict__ BhG,
    float* __restrict__ out)
{
    __shared__ float Rt[BN][W + 4];                  // 33.8 KB, stride 132 (16B-aligned rows)
    __shared__ unsigned long long mslot[BN * 5];     // 2.5 KB: [row][wv], stride 5
    __shared__ int   cand[BN][4];
    __shared__ float dve[BN][4];
    __shared__ int   widx[BN];

    const int tid = threadIdx.x;
    const int wv  = tid >> 6;      // 0..3: owns kb in [wv*16, wv*16+16)
    const int ln  = tid & 63;
    const int col = ln & 15;
    const int n0  = blockIdx.x * BN;

    // ---- initial residual = X ----
    for (int e = tid; e < BN * 32; e += NT){
        const int row = e >> 5, q = e & 31;
        const float4 v = *(const float4*)(X + (size_t)(n0 + row) * W + q * 4);
        *(float4*)(&Rt[row][q * 4]) = v;
    }

    for (int st = 0; st < C; ++st){
        const float*  cb  = CB + (size_t)st * K * W;
        const float4* cb4 = (const float4*)cb;
        const f16*    BhS = BhG + (size_t)st * 131072;   // 64 kb * 4 q * 64 ln * 8

        __syncthreads();   // Rt stable

        // ---- per-lane c2 for this wave's 16 kb (16 regs, once per stage) ----
        float c2reg[16];
        #pragma unroll
        for (int kbi = 0; kbi < 16; ++kbi)
            c2reg[kbi] = c2g[st * K + (((wv * 16 + kbi) << 4) + col)];

        // ---- A fragments: 64 rows, f32->f16 direct from Rt (held whole stage) ----
        f16x8 a[4][4];
        #pragma unroll
        for (int rbl = 0; rbl < 4; ++rbl){
            #pragma unroll
            for (int q = 0; q < 4; ++q){
                const int row = rbl * 16 + (ln & 15);
                const int w0  = q * 32 + ((ln >> 4) << 3);
                const float* rp = &Rt[row][w0];
                f16x8 h;
                #pragma unroll
                for (int j = 0; j < 8; ++j) h[j] = (f16)rp[j];
                a[rbl][q] = h;
            }
        }

        unsigned s1[4][4], s2[4][4];
        #pragma unroll
        for (int i = 0; i < 4; ++i)
            #pragma unroll
            for (int j = 0; j < 4; ++j){ s1[i][j] = 0xFFFFFFFFu; s2[i][j] = 0xFFFFFFFFu; }

        // ---- MFMA scan over this wave's 16 kb ----
        #pragma unroll 1
        for (int kbi = 0; kbi < 16; ++kbi){
            const int kb = wv * 16 + kbi;
            f16x8 bh0 = *(const f16x8*)(BhS + ((size_t)(kb * 4 + 0) * 64 + ln) * 8);
            f16x8 bh1 = *(const f16x8*)(BhS + ((size_t)(kb * 4 + 1) * 64 + ln) * 8);
            f16x8 bh2 = *(const f16x8*)(BhS + ((size_t)(kb * 4 + 2) * 64 + ln) * 8);
            f16x8 bh3 = *(const f16x8*)(BhS + ((size_t)(kb * 4 + 3) * 64 + ln) * 8);
            const unsigned kpk = (unsigned)((kb << 4) + col);
            const float    c2v = c2reg[kbi];

            #pragma unroll
            for (int rbl = 0; rbl < 4; ++rbl){
                f32x4 acc = {0.f, 0.f, 0.f, 0.f};
                acc = __builtin_amdgcn_mfma_f32_16x16x32_f16(a[rbl][0], bh0, acc, 0, 0, 0);
                acc = __builtin_amdgcn_mfma_f32_16x16x32_f16(a[rbl][1], bh1, acc, 0, 0, 0);
                acc = __builtin_amdgcn_mfma_f32_16x16x32_f16(a[rbl][2], bh2, acc, 0, 0, 0);
                acc = __builtin_amdgcn_mfma_f32_16x16x32_f16(a[rbl][3], bh3, acc, 0, 0, 0);
                PACK_INS(acc[0], c2v, kpk, s1[rbl][0], s2[rbl][0]);
                PACK_INS(acc[1], c2v, kpk, s1[rbl][1], s2[rbl][1]);
                PACK_INS(acc[2], c2v, kpk, s1[rbl][2], s2[rbl][2]);
                PACK_INS(acc[3], c2v, kpk, s1[rbl][3], s2[rbl][3]);
            }
        }

        // ---- flush: DPP top-2 across the 16 col-lanes -> per-wave slot ----
        #pragma unroll
        for (int rbl = 0; rbl < 4; ++rbl){
            #pragma unroll
            for (int rg = 0; rg < 4; ++rg){
                unsigned p1 = s1[rbl][rg], p2 = s2[rbl][rg];
                DPP_TOP2(p1, p2, 0x121)   // row_ror:1
                DPP_TOP2(p1, p2, 0x122)   // row_ror:2
                DPP_TOP2(p1, p2, 0x124)   // row_ror:4
                DPP_TOP2(p1, p2, 0x128)   // row_ror:8
                if (col == 0){
                    const int row = rbl * 16 + ((ln >> 4) << 2) + rg;
                    mslot[row * 5 + wv] =
                        ((unsigned long long)p2 << 32) | (unsigned long long)p1;
                }
            }
        }
        __syncthreads();   // all wave top-2 written

        // ---- merge: global top-4 per row from 4 waves x top-2 ----
        if (tid < BN){
            unsigned c0 = 0xFFFFFFFFu, c1 = 0xFFFFFFFFu, c2m = 0xFFFFFFFFu, c3 = 0xFFFFFFFFu;
            #pragma unroll
            for (int i = 0; i < 4; ++i){
                const unsigned long long v = mslot[tid * 5 + i];
                const unsigned lo = (unsigned)v, hi = (unsigned)(v >> 32);
                INS4(lo, c0, c1, c2m, c3);
                INS4(hi, c0, c1, c2m, c3);
            }
            cand[tid][0] = (int)(c0 & 1023u);
            cand[tid][1] = (int)(c1 & 1023u);
            cand[tid][2] = (int)(c2m & 1023u);
            cand[tid][3] = (int)(c3 & 1023u);
        }
        __syncthreads();

        // ---- exact XLA-bits re-eval of 4 candidates (256 threads = 64 rows x 4) ----
        {
            const int row = tid >> 2, cd = tid & 3;
            const int k = cand[row][cd];
            const float* cw = cb + (size_t)k * W;
            float r2 = 0.f, dot = 0.f;
            for (int w = 0; w < W; ++w){
                const float rv = Rt[row][w];
                r2  = faddr(r2, fmulr(rv, rv));
                dot = __fmaf_rn(rv, cw[w], dot);
            }
            dve[row][cd] = faddr(fsubr(r2, faddr(dot, dot)), c2g[st * K + k]);
        }
        __syncthreads();

        // ---- decide: lexicographic (d2, k) min among 4 = XLA first-min ----
        if (tid < BN){
            float bd = dve[tid][0]; int bk = cand[tid][0];
            #pragma unroll
            for (int j = 1; j < 4; ++j){
                const float d = dve[tid][j]; const int k = cand[tid][j];
                if (d < bd || (d == bd && k < bk)){ bd = d; bk = k; }
            }
            widx[tid] = bk;
            out[(size_t)st * NRW + (n0 + tid)] = (float)bk;
            out[(size_t)C * NRW + (size_t)(n0 + tid) * C + st] = __fsqrt_rn(fmaxf(bd, 0.f));
        }
        __syncthreads();

        // ---- residual -= cb[idx], elementwise f32 (bit-exact) ----
        if (st < C - 1){
            for (int e = tid; e < BN * 32; e += NT){
                const int row = e >> 5, q = e & 31;
                const float4 v = cb4[(size_t)widx[row] * 32 + q];
                float* rp = &Rt[row][q * 4];
                rp[0] = fsubr(rp[0], v.x);
                rp[1] = fsubr(rp[1], v.y);
                rp[2] = fsubr(rp[2], v.z);
                rp[3] = fsubr(rp[3], v.w);
            }
        }
    }
}

extern "C" void kernel_launch(void* const* d_in, const int* in_sizes, int n_in,
                              void* d_out, int out_size, void* d_ws, size_t ws_size,
                              hipStream_t stream) {
    const float* X  = (const float*)d_in[0];
    const float* CB = (const float*)d_in[1];
    float* out = (float*)d_out;

    float* c2g = (float*)d_ws;                    // 16 KB
    f16*   Bh  = (f16*)((char*)d_ws + 16384);     // 1 MB

    c2_kernel<<<dim3((C * K + 255) / 256), 256, 0, stream>>>(CB, c2g);
    split_kernel<<<dim3(C * K * 16 / 256), 256, 0, stream>>>(CB, Bh);
    rq15_kernel<<<dim3(NRW / BN), NT, 0, stream>>>(X, CB, c2g, Bh, out);
}